// Round 1
// baseline (74715.417 us; speedup 1.0000x reference)
//
#include <hip/hip_runtime.h>
#include <math.h>

#define Bb 32
#define Lmax 400
#define Tt 64
#define Ee 256
#define Hh 512
#define H2 1024
#define Vv 32000
#define OOV 100
#define VX (Vv+OOV)
#define PAD_ID 0
#define UNK_ID 1
#define START_ID 2

__device__ __forceinline__ float sigf(float x){ return 1.0f/(1.0f+expf(-x)); }

// ---------------- encoder: one step, both directions fused ----------------
// thread = (dir, b, n), n in [0,512). 128 blocks x 256 threads = 32768 threads.
// h state lives in enc_out rows (prev step's row); c double use in-place (only owner thread touches it).
__global__ __launch_bounds__(256) void enc_step_k(
    const float* __restrict__ emb, const int* __restrict__ x,
    const float* __restrict__ Wi_f, const float* __restrict__ Wh_f, const float* __restrict__ b_f,
    const float* __restrict__ Wi_b, const float* __restrict__ Wh_b, const float* __restrict__ b_b,
    float* __restrict__ c_f, float* __restrict__ c_b,
    float* __restrict__ enc_out, int t)
{
  int idx = blockIdx.x*256 + threadIdx.x;
  int dir = idx >> 14;
  int r   = idx & 16383;
  int b   = r >> 9;
  int n   = r & 511;
  const float* Wi = dir ? Wi_b : Wi_f;
  const float* Wh = dir ? Wh_b : Wh_f;
  const float* bbias = dir ? b_b : b_f;
  float* c = dir ? c_b : c_f;
  int tt = dir ? (Lmax-1-t) : t;
  int tok = x[b*Lmax+tt];
  const float* xr = emb + (size_t)tok*Ee;
  float zi = bbias[n], zf = bbias[Hh+n], zg = bbias[2*Hh+n], zo = bbias[3*Hh+n];
  #pragma unroll 4
  for (int k = 0; k < Ee; ++k) {
    float xv = xr[k];
    const float* w = Wi + (size_t)k*(4*Hh);
    zi = fmaf(xv, w[n], zi);      zf = fmaf(xv, w[Hh+n], zf);
    zg = fmaf(xv, w[2*Hh+n], zg); zo = fmaf(xv, w[3*Hh+n], zo);
  }
  if (t > 0) {
    int pt = dir ? (tt+1) : (tt-1);
    const float* hb = enc_out + ((size_t)b*Lmax + pt)*H2 + dir*Hh;
    #pragma unroll 4
    for (int k = 0; k < Hh; ++k) {
      float hv = hb[k];
      const float* w = Wh + (size_t)k*(4*Hh);
      zi = fmaf(hv, w[n], zi);      zf = fmaf(hv, w[Hh+n], zf);
      zg = fmaf(hv, w[2*Hh+n], zg); zo = fmaf(hv, w[3*Hh+n], zo);
    }
  }
  float cv = (t==0) ? 0.0f : c[b*Hh+n];
  float cn = sigf(zf)*cv + sigf(zi)*tanhf(zg);
  float hn = sigf(zo)*tanhf(cn);
  c[b*Hh+n] = cn;
  enc_out[((size_t)b*Lmax+tt)*H2 + dir*Hh + n] = hn;
}

// ---------------- decoder init: dec_h0 = [hN_f, hN_b], acc=0, dec_in=START ----
__global__ __launch_bounds__(256) void init_dec_k(
    const float* __restrict__ enc_out, float* __restrict__ cat_buf,
    float* __restrict__ accum, int* __restrict__ dec_in)
{
  int idx = blockIdx.x*256 + threadIdx.x;
  if (idx < Bb*H2) {
    int b = idx >> 10, n = idx & 1023;
    float v = (n < Hh) ? enc_out[((size_t)b*Lmax + (Lmax-1))*H2 + n]   // hN_f
                       : enc_out[(size_t)b*Lmax*H2 + n];               // hN_b at l=0, cols 512..
    cat_buf[b*3*H2 + n] = v;
  }
  if (idx < Bb*Lmax) accum[idx] = 0.0f;
  if (idx < Bb) dec_in[idx] = START_ID;
}

// ---------------- GRU matmuls: zi = emb@Wi + b (K=256); zh = h@Wh (K=1024) ----
// thread = (b fast, n), 8 n per block, 384 blocks.
__global__ __launch_bounds__(256) void gru_mm_k(
    const float* __restrict__ emb, const int* __restrict__ dec_in,
    const float* __restrict__ cat_buf, const float* __restrict__ Wi,
    const float* __restrict__ Wh, const float* __restrict__ bias,
    float* __restrict__ zi_buf, float* __restrict__ zh_buf)
{
  int tid = threadIdx.x;
  int b = tid & 31;
  int n = blockIdx.x*8 + (tid >> 5);
  const float* er = emb + (size_t)dec_in[b]*Ee;
  const float* hr = cat_buf + b*3*H2;      // dec_h lives in cat[:,0:1024]
  float zi = bias[n], zh = 0.0f;
  #pragma unroll 4
  for (int k = 0; k < Ee; ++k) zi = fmaf(er[k], Wi[(size_t)k*3*H2 + n], zi);
  #pragma unroll 4
  for (int k = 0; k < H2; ++k) zh = fmaf(hr[k], Wh[(size_t)k*3*H2 + n], zh);
  zi_buf[b*3*H2+n] = zi;
  zh_buf[b*3*H2+n] = zh;
}

__global__ __launch_bounds__(256) void gru_comb_k(
    const float* __restrict__ zi_buf, const float* __restrict__ zh_buf,
    float* __restrict__ cat_buf, float* __restrict__ prebuf, int t)
{
  int idx = blockIdx.x*256 + threadIdx.x;   // 32768
  int b = idx >> 10, n = idx & 1023;
  const float* zi = zi_buf + b*3*H2;
  const float* zh = zh_buf + b*3*H2;
  float r  = sigf(zi[n] + zh[n]);
  float z  = sigf(zi[H2+n] + zh[H2+n]);
  float nn = tanhf(zi[2*H2+n] + r*zh[2*H2+n]);
  float hold = cat_buf[b*3*H2 + n];
  float h = (1.0f - z)*nn + z*hold;
  cat_buf[b*3*H2 + n] = h;
  prebuf[((size_t)b*Tt + t)*H2 + n] = h;    // row t; only rows < t are read this step
}

// ---------------- attention queries: q = h@W_enc_att, qd = h@W_dec_att ----------
__global__ __launch_bounds__(256) void qq_k(
    const float* __restrict__ cat_buf, const float* __restrict__ Wea,
    const float* __restrict__ Wda, float* __restrict__ q, float* __restrict__ qd)
{
  int tid = threadIdx.x;
  int b = tid & 31;
  int n = blockIdx.x*8 + (tid>>5);
  const float* hr = cat_buf + b*3*H2;
  float s1 = 0.0f, s2 = 0.0f;
  #pragma unroll 4
  for (int k = 0; k < H2; ++k) {
    float hv = hr[k];
    s1 = fmaf(hv, Wea[(size_t)k*H2+n], s1);
    s2 = fmaf(hv, Wda[(size_t)k*H2+n], s2);
  }
  q[b*H2+n] = s1; qd[b*H2+n] = s2;
}

// ---------------- attention scores: one wave per (b, row); rows = 400 enc + 64 dec --
__global__ __launch_bounds__(256) void att_sc_k(
    const float* __restrict__ q, const float* __restrict__ qd,
    const float* __restrict__ enc_out, const float* __restrict__ prebuf,
    float* __restrict__ esc, float* __restrict__ ed, int t)
{
  int w = blockIdx.x*4 + (threadIdx.x >> 6);
  int lane = threadIdx.x & 63;
  int b = w / 464;
  int row = w - b*464;
  if (b >= Bb) return;
  float s = 0.0f;
  if (row < Lmax) {
    const float* qr = q + b*H2;
    const float* er = enc_out + ((size_t)b*Lmax + row)*H2;
    #pragma unroll
    for (int i = 0; i < H2/64; ++i) s = fmaf(qr[lane+64*i], er[lane+64*i], s);
  } else {
    int tp = row - Lmax;
    if (tp >= t) { if (lane==0) ed[b*Tt+tp] = 0.0f; return; }  // masked; avoid stale prebuf
    const float* qr = qd + b*H2;
    const float* pr = prebuf + ((size_t)b*Tt + tp)*H2;
    #pragma unroll
    for (int i = 0; i < H2/64; ++i) s = fmaf(qr[lane+64*i], pr[lane+64*i], s);
  }
  for (int o = 32; o > 0; o >>= 1) s += __shfl_xor(s, o);
  if (lane == 0) { if (row < Lmax) esc[b*Lmax+row] = s; else ed[b*Tt + (row-Lmax)] = s; }
}

// ---------------- temporal-attention normalize + intra-dec softmax (block per b) ----
__global__ __launch_bounds__(256) void att_norm_k(
    const float* __restrict__ esc, float* __restrict__ accum,
    float* __restrict__ enc_att, const float* __restrict__ ed,
    float* __restrict__ dec_att, int t)
{
  __shared__ float red[256];
  int b = blockIdx.x, tid = threadIdx.x;
  float loc = 0.0f;
  for (int l = tid; l < Lmax; l += 256) {
    float ee = expf(esc[b*Lmax + l]);
    float a  = accum[b*Lmax + l];
    float un = (t == 0) ? ee : ee / (a + 1e-10f);
    accum[b*Lmax + l] = a + ee;
    enc_att[b*Lmax + l] = un;
    loc += un;
  }
  red[tid] = loc; __syncthreads();
  for (int s = 128; s > 0; s >>= 1) { if (tid < s) red[tid] += red[tid+s]; __syncthreads(); }
  float inv = 1.0f / red[0];
  for (int l = tid; l < Lmax; l += 256) enc_att[b*Lmax+l] *= inv;
  if (tid < 64) {   // intra-decoder softmax over t' < t (wave 0 only)
    int lane = tid;
    if (t == 0) { dec_att[b*Tt+lane] = 0.0f; }
    else {
      float v = (lane < t) ? ed[b*Tt+lane] : -INFINITY;
      float m = v;
      for (int o = 32; o > 0; o >>= 1) m = fmaxf(m, __shfl_xor(m, o));
      float p = (lane < t) ? expf(v - m) : 0.0f;
      float ssum = p;
      for (int o = 32; o > 0; o >>= 1) ssum += __shfl_xor(ssum, o);
      dec_att[b*Tt+lane] = p / ssum;
    }
  }
}

// ---------------- contexts -> cat[:,1024:2048]=enc_ctx, cat[:,2048:3072]=dec_ctx ----
__global__ __launch_bounds__(256) void ctx_k(
    const float* __restrict__ enc_att, const float* __restrict__ enc_out,
    const float* __restrict__ dec_att, const float* __restrict__ prebuf,
    float* __restrict__ cat_buf, int t)
{
  int idx = blockIdx.x*256 + threadIdx.x;  // 32768
  int b = idx >> 10, k = idx & 1023;
  float ec = 0.0f;
  const float* ar = enc_att + b*Lmax;
  const float* er = enc_out + (size_t)b*Lmax*H2 + k;
  for (int l = 0; l < Lmax; ++l) ec = fmaf(ar[l], er[(size_t)l*H2], ec);
  float dc = 0.0f;
  const float* dr = dec_att + b*Tt;
  const float* pr = prebuf + (size_t)b*Tt*H2 + k;
  for (int tp = 0; tp < t; ++tp) dc = fmaf(dr[tp], pr[(size_t)tp*H2], dc);
  cat_buf[b*3*H2 + H2   + k] = ec;
  cat_buf[b*3*H2 + 2*H2 + k] = dc;
}

// ---------------- p_gen = sigmoid(cat @ Wp + bp): one wave per b ----------------
__global__ __launch_bounds__(64) void pgen_k(
    const float* __restrict__ cat_buf, const float* __restrict__ Wp,
    const float* __restrict__ bp, float* __restrict__ pg)
{
  int b = blockIdx.x, lane = threadIdx.x;
  const float* cr = cat_buf + b*3*H2;
  float s = 0.0f;
  #pragma unroll
  for (int i = 0; i < 3*H2/64; ++i) s = fmaf(cr[lane+64*i], Wp[lane+64*i], s);
  for (int o = 32; o > 0; o >>= 1) s += __shfl_xor(s, o);
  if (lane == 0) pg[b] = sigf(s + bp[0]);
}

// ---------------- logits = cat @ Wv + bv : LDS-tiled [32 x 128] per block ----------
__global__ __launch_bounds__(256) void wv_mm_k(
    const float* __restrict__ cat_buf, const float* __restrict__ Wv,
    const float* __restrict__ bv, float* __restrict__ logits)
{
  __shared__ float As[32][33];
  __shared__ float Wsh[32][128];
  int tid = threadIdx.x;
  int n0 = blockIdx.x*128;
  int tx = tid & 31, ty = tid >> 5;   // tx: 4-col group, ty: 4-row group
  float acc[4][4] = {};
  for (int k0 = 0; k0 < 3*H2; k0 += 32) {
    #pragma unroll
    for (int i = 0; i < 4; ++i) {
      int a = tid*4+i;
      As[a>>5][a&31] = cat_buf[(size_t)(a>>5)*3*H2 + k0 + (a&31)];
    }
    #pragma unroll
    for (int j = 0; j < 16; ++j) {
      int a = j*256+tid;
      Wsh[a>>7][a&127] = Wv[(size_t)(k0+(a>>7))*Vv + n0 + (a&127)];
    }
    __syncthreads();
    #pragma unroll
    for (int kk = 0; kk < 32; ++kk) {
      float a0 = As[ty*4+0][kk], a1 = As[ty*4+1][kk], a2 = As[ty*4+2][kk], a3 = As[ty*4+3][kk];
      float w0 = Wsh[kk][tx*4+0], w1 = Wsh[kk][tx*4+1], w2 = Wsh[kk][tx*4+2], w3 = Wsh[kk][tx*4+3];
      acc[0][0]=fmaf(a0,w0,acc[0][0]); acc[0][1]=fmaf(a0,w1,acc[0][1]); acc[0][2]=fmaf(a0,w2,acc[0][2]); acc[0][3]=fmaf(a0,w3,acc[0][3]);
      acc[1][0]=fmaf(a1,w0,acc[1][0]); acc[1][1]=fmaf(a1,w1,acc[1][1]); acc[1][2]=fmaf(a1,w2,acc[1][2]); acc[1][3]=fmaf(a1,w3,acc[1][3]);
      acc[2][0]=fmaf(a2,w0,acc[2][0]); acc[2][1]=fmaf(a2,w1,acc[2][1]); acc[2][2]=fmaf(a2,w2,acc[2][2]); acc[2][3]=fmaf(a2,w3,acc[2][3]);
      acc[3][0]=fmaf(a3,w0,acc[3][0]); acc[3][1]=fmaf(a3,w1,acc[3][1]); acc[3][2]=fmaf(a3,w2,acc[3][2]); acc[3][3]=fmaf(a3,w3,acc[3][3]);
    }
    __syncthreads();
  }
  #pragma unroll
  for (int i = 0; i < 4; ++i)
    #pragma unroll
    for (int j = 0; j < 4; ++j) {
      int n = n0 + tx*4 + j;
      logits[(size_t)(ty*4+i)*Vv + n] = acc[i][j] + bv[n];
    }
}

// ---------------- softmax -> final[:, :V] = (1-pg)*softmax; zero OOV tail ----------
__global__ __launch_bounds__(256) void smax_k(
    const float* __restrict__ logits, const float* __restrict__ pg, float* __restrict__ fin)
{
  __shared__ float red[256];
  int b = blockIdx.x, tid = threadIdx.x;
  const float* lr = logits + (size_t)b*Vv;
  float* fr = fin + (size_t)b*VX;
  float m = -INFINITY;
  for (int n = tid; n < Vv; n += 256) m = fmaxf(m, lr[n]);
  red[tid] = m; __syncthreads();
  for (int s = 128; s > 0; s >>= 1) { if (tid < s) red[tid] = fmaxf(red[tid], red[tid+s]); __syncthreads(); }
  m = red[0]; __syncthreads();
  float sum = 0.0f;
  for (int n = tid; n < Vv; n += 256) { float p = expf(lr[n]-m); fr[n] = p; sum += p; }
  red[tid] = sum; __syncthreads();
  for (int s = 128; s > 0; s >>= 1) { if (tid < s) red[tid] += red[tid+s]; __syncthreads(); }
  float scale = (1.0f - pg[b]) / red[0];
  for (int n = tid; n < Vv; n += 256) fr[n] *= scale;
  for (int n = Vv+tid; n < VX; n += 256) fr[n] = 0.0f;
}

// ---------------- pointer scatter: final[b, ev[b,l]] += pg*enc_att ------------------
__global__ __launch_bounds__(256) void scat_k(
    const int* __restrict__ ev, const float* __restrict__ enc_att,
    const float* __restrict__ pg, float* __restrict__ fin)
{
  int idx = blockIdx.x*256 + threadIdx.x;  // 12800
  if (idx >= Bb*Lmax) return;
  int b = idx / Lmax;
  atomicAdd(&fin[(size_t)b*VX + ev[idx]], pg[b]*enc_att[idx]);
}

// ---------------- argmax (first-index tiebreak) + loss + next input -----------------
__global__ __launch_bounds__(256) void amax_k(
    const float* __restrict__ fin, const int* __restrict__ tgt_y,
    float* __restrict__ out, int* __restrict__ dec_in, int t)
{
  __shared__ float rv[256]; __shared__ int ri[256];
  int b = blockIdx.x, tid = threadIdx.x;
  const float* fr = fin + (size_t)b*VX;
  float best = -INFINITY; int bi = 0x7fffffff;
  for (int n = tid; n < VX; n += 256) { float v = fr[n]; if (v > best) { best = v; bi = n; } }
  rv[tid] = best; ri[tid] = bi; __syncthreads();
  for (int s = 128; s > 0; s >>= 1) {
    if (tid < s) {
      float v2 = rv[tid+s]; int i2 = ri[tid+s];
      if (v2 > rv[tid] || (v2 == rv[tid] && i2 < ri[tid])) { rv[tid] = v2; ri[tid] = i2; }
    }
    __syncthreads();
  }
  if (tid == 0) {
    int am = ri[0];
    int tg = tgt_y[b*Tt + t];
    float loss = (tg != PAD_ID) ? -logf(fr[tg] + 1e-12f) : 0.0f;
    out[b*Tt + t] = (float)am;              // ys (int indices written as f32)
    out[Bb*Tt + b*Tt + t] = loss;           // losses
    dec_in[b] = (am >= Vv) ? UNK_ID : am;
  }
}

extern "C" void kernel_launch(void* const* d_in, const int* in_sizes, int n_in,
                              void* d_out, int out_size, void* d_ws, size_t ws_size,
                              hipStream_t stream)
{
  const int*   x    = (const int*)  d_in[0];
  const int*   tgt  = (const int*)  d_in[2];
  const int*   ev   = (const int*)  d_in[3];
  const float* emb  = (const float*)d_in[5];
  const float* Wi_f = (const float*)d_in[6];
  const float* Wh_f = (const float*)d_in[7];
  const float* b_f  = (const float*)d_in[8];
  const float* Wi_b = (const float*)d_in[9];
  const float* Wh_b = (const float*)d_in[10];
  const float* b_b  = (const float*)d_in[11];
  const float* dWi  = (const float*)d_in[12];
  const float* dWh  = (const float*)d_in[13];
  const float* db   = (const float*)d_in[14];
  const float* Wea  = (const float*)d_in[15];
  const float* Wda  = (const float*)d_in[16];
  const float* Wv   = (const float*)d_in[17];
  const float* bv   = (const float*)d_in[18];
  const float* Wp   = (const float*)d_in[19];
  const float* bp   = (const float*)d_in[20];
  float* out = (float*)d_out;

  float* ws = (float*)d_ws;
  size_t off = 0;
  float* enc_out = ws + off; off += (size_t)Bb*Lmax*H2;   // 13.1M
  float* c_f     = ws + off; off += Bb*Hh;
  float* c_b     = ws + off; off += Bb*Hh;
  float* cat_buf = ws + off; off += Bb*3*H2;              // [dec_h | enc_ctx | dec_ctx]
  float* prebuf  = ws + off; off += (size_t)Bb*Tt*H2;
  float* accum   = ws + off; off += Bb*Lmax;
  float* zi_buf  = ws + off; off += Bb*3*H2;
  float* zh_buf  = ws + off; off += Bb*3*H2;
  float* q       = ws + off; off += Bb*H2;
  float* qd      = ws + off; off += Bb*H2;
  float* esc     = ws + off; off += Bb*Lmax;
  float* enc_att = ws + off; off += Bb*Lmax;
  float* ed      = ws + off; off += Bb*Tt;
  float* dec_att = ws + off; off += Bb*Tt;
  float* pg      = ws + off; off += Bb;
  float* logits  = ws + off; off += (size_t)Bb*Vv;
  float* fin     = ws + off; off += (size_t)Bb*VX;
  int*   dec_in  = (int*)(ws + off); off += Bb;
  // total ~17.7M floats ~ 71 MB

  for (int t = 0; t < Lmax; ++t)
    enc_step_k<<<128,256,0,stream>>>(emb,x,Wi_f,Wh_f,b_f,Wi_b,Wh_b,b_b,c_f,c_b,enc_out,t);

  init_dec_k<<<128,256,0,stream>>>(enc_out,cat_buf,accum,dec_in);

  for (int t = 0; t < Tt; ++t) {
    gru_mm_k  <<<384,256,0,stream>>>(emb,dec_in,cat_buf,dWi,dWh,db,zi_buf,zh_buf);
    gru_comb_k<<<128,256,0,stream>>>(zi_buf,zh_buf,cat_buf,prebuf,t);
    qq_k      <<<128,256,0,stream>>>(cat_buf,Wea,Wda,q,qd);
    att_sc_k  <<<3712,256,0,stream>>>(q,qd,enc_out,prebuf,esc,ed,t);
    att_norm_k<<<32,256,0,stream>>>(esc,accum,enc_att,ed,dec_att,t);
    ctx_k     <<<128,256,0,stream>>>(enc_att,enc_out,dec_att,prebuf,cat_buf,t);
    pgen_k    <<<32,64,0,stream>>>(cat_buf,Wp,bp,pg);
    wv_mm_k   <<<250,256,0,stream>>>(cat_buf,Wv,bv,logits);
    smax_k    <<<32,256,0,stream>>>(logits,pg,fin);
    scat_k    <<<50,256,0,stream>>>(ev,enc_att,pg,fin);
    amax_k    <<<32,256,0,stream>>>(fin,tgt,out,dec_in,t);
  }
}

// Round 2
// 44092.609 us; speedup vs baseline: 1.6945x; 1.6945x over previous
//
#include <hip/hip_runtime.h>
#include <math.h>

#define Bb 32
#define Lmax 400
#define Tt 64
#define Ee 256
#define Hh 512
#define H2 1024
#define Vv 32000
#define OOV 100
#define VX (Vv+OOV)
#define PAD_ID 0
#define UNK_ID 1
#define START_ID 2

__device__ __forceinline__ float sigf(float x){ return 1.0f/(1.0f+expf(-x)); }
__device__ __forceinline__ float bf2f(unsigned int u){ u <<= 16; return __uint_as_float(u); }

// ================= encoder weight packing =================
// wip[(dir*256+k)*512+n] = float4{Wi[k][g*512+n], g=0..3}; whp analog (K=512); bp[dir*512+n]=bias gates
__global__ __launch_bounds__(256) void pack_enc_k(
    const float* __restrict__ Wi_f, const float* __restrict__ Wh_f, const float* __restrict__ b_f,
    const float* __restrict__ Wi_b, const float* __restrict__ Wh_b, const float* __restrict__ b_b,
    float4* __restrict__ wip, float4* __restrict__ whp, float4* __restrict__ bp)
{
  int o = blockIdx.x*256 + threadIdx.x;
  if (o < 2*256*512) {
    int n = o & 511; int k = (o >> 9) & 255; int dir = o >> 17;
    const float* W = dir ? Wi_b : Wi_f;
    wip[o] = make_float4(W[k*2048+n], W[k*2048+512+n], W[k*2048+1024+n], W[k*2048+1536+n]);
  }
  if (o < 2*512*512) {
    int n = o & 511; int k = (o >> 9) & 511; int dir = o >> 18;
    const float* W = dir ? Wh_b : Wh_f;
    whp[o] = make_float4(W[k*2048+n], W[k*2048+512+n], W[k*2048+1024+n], W[k*2048+1536+n]);
  }
  if (o < 2*512) {
    int n = o & 511; int dir = o >> 9;
    const float* bs = dir ? b_b : b_f;
    bp[o] = make_float4(bs[n], bs[512+n], bs[1024+n], bs[1536+n]);
  }
}

// ================= encoder step: K-split-4, LDS-staged weights =================
// grid 256 = dir(2) x ngroup(128, 4 n each); block 512 = b(32) x nl(4) x ks(4)
__global__ __launch_bounds__(512) void enc_step2_k(
    const float4* __restrict__ wip, const float4* __restrict__ whp, const float4* __restrict__ bp,
    const float* __restrict__ emb, const int* __restrict__ x,
    float* __restrict__ c_buf, float* __restrict__ enc_out, int t)
{
  __shared__ float4 wi_s[256*4];
  __shared__ float4 wh_s[512*4];
  __shared__ float4 red_s[4*128];
  int bx = blockIdx.x;
  int dir = bx >> 7, ng = bx & 127;
  int tid = threadIdx.x;
  int b = tid & 31, nl = (tid >> 5) & 3, ks = tid >> 7;
  int n = ng*4 + nl;
  for (int i = tid; i < 1024; i += 512) {
    int k = i >> 2, l = i & 3;
    wi_s[i] = wip[(dir*256 + k)*512 + ng*4 + l];
  }
  for (int i = tid; i < 2048; i += 512) {
    int k = i >> 2, l = i & 3;
    wh_s[i] = whp[(dir*512 + k)*512 + ng*4 + l];
  }
  __syncthreads();
  int tt = dir ? (Lmax-1-t) : t;
  int tok = x[b*Lmax + tt];
  const float* xr = emb + (size_t)tok*Ee;
  float4 acc = make_float4(0.f,0.f,0.f,0.f);
  if (t > 0) {
    int pt = dir ? (tt+1) : (tt-1);
    const float* hb = enc_out + ((size_t)b*Lmax + pt)*H2 + dir*Hh;
    #pragma unroll 8
    for (int k = ks*128; k < ks*128+128; ++k) {
      float hv = hb[k]; float4 w = wh_s[k*4 + nl];
      acc.x = fmaf(hv,w.x,acc.x); acc.y = fmaf(hv,w.y,acc.y);
      acc.z = fmaf(hv,w.z,acc.z); acc.w = fmaf(hv,w.w,acc.w);
    }
  }
  #pragma unroll 8
  for (int k = ks*64; k < ks*64+64; ++k) {
    float xv = xr[k]; float4 w = wi_s[k*4 + nl];
    acc.x = fmaf(xv,w.x,acc.x); acc.y = fmaf(xv,w.y,acc.y);
    acc.z = fmaf(xv,w.z,acc.z); acc.w = fmaf(xv,w.w,acc.w);
  }
  red_s[ks*128 + (tid & 127)] = acc;
  __syncthreads();
  if (tid < 128) {
    float4 a0 = red_s[tid], a1 = red_s[128+tid], a2 = red_s[256+tid], a3 = red_s[384+tid];
    float4 bb = bp[dir*512 + n];
    float zi = a0.x+a1.x+a2.x+a3.x + bb.x;
    float zf = a0.y+a1.y+a2.y+a3.y + bb.y;
    float zg = a0.z+a1.z+a2.z+a3.z + bb.z;
    float zo = a0.w+a1.w+a2.w+a3.w + bb.w;
    int ci = (dir*32 + b)*Hh + n;
    float cv = (t==0) ? 0.f : c_buf[ci];
    float cn = sigf(zf)*cv + sigf(zi)*tanhf(zg);
    float hn = sigf(zo)*tanhf(cn);
    c_buf[ci] = cn;
    enc_out[((size_t)b*Lmax + tt)*H2 + dir*Hh + n] = hn;
  }
}

// ================= decoder init =================
__global__ __launch_bounds__(256) void init_dec_k(
    const float* __restrict__ enc_out, float* __restrict__ cat_buf,
    float* __restrict__ accum, int* __restrict__ dec_in)
{
  int idx = blockIdx.x*256 + threadIdx.x;
  if (idx < Bb*H2) {
    int b = idx >> 10, n = idx & 1023;
    float v = (n < Hh) ? enc_out[((size_t)b*Lmax + (Lmax-1))*H2 + n]
                       : enc_out[(size_t)b*Lmax*H2 + n];
    cat_buf[b*3*H2 + n] = v;
  }
  if (idx < Bb*Lmax) accum[idx] = 0.0f;
  if (idx < Bb) dec_in[idx] = START_ID;
}

// ================= GRU matmuls: coalesced (n fast, b uniform per wave) =================
// grid 384 = ng(48 x 64n) x bg(8 x 4b); block 256 = nl(64) x bl(4)
__global__ __launch_bounds__(256) void gru_mm_k(
    const float* __restrict__ emb, const int* __restrict__ dec_in,
    const float* __restrict__ cat_buf, const float* __restrict__ Wi,
    const float* __restrict__ Wh, const float* __restrict__ bias,
    float* __restrict__ zi_buf, float* __restrict__ zh_buf, float* __restrict__ pg_raw)
{
  int bx = blockIdx.x;
  int ng = bx % 48, bg = bx / 48;
  int nl = threadIdx.x & 63, bl = threadIdx.x >> 6;
  int n = ng*64 + nl, b = bg*4 + bl;
  const float* er = emb + (size_t)dec_in[b]*Ee;
  const float* hr = cat_buf + b*3*H2;
  float zi = bias[n], zh = 0.f;
  #pragma unroll 4
  for (int k = 0; k < Ee; ++k) zi = fmaf(er[k], Wi[(size_t)k*3*H2 + n], zi);
  #pragma unroll 4
  for (int k = 0; k < H2; ++k) zh = fmaf(hr[k], Wh[(size_t)k*3*H2 + n], zh);
  zi_buf[b*3*H2+n] = zi;
  zh_buf[b*3*H2+n] = zh;
  if (bx == 0 && threadIdx.x < Bb) pg_raw[threadIdx.x] = 0.0f;   // zero for this step's atomics
}

__global__ __launch_bounds__(256) void gru_comb_k(
    const float* __restrict__ zi_buf, const float* __restrict__ zh_buf,
    float* __restrict__ cat_buf, float* __restrict__ prebuf, int t)
{
  int idx = blockIdx.x*256 + threadIdx.x;   // 32768
  int b = idx >> 10, n = idx & 1023;
  const float* zi = zi_buf + b*3*H2;
  const float* zh = zh_buf + b*3*H2;
  float r  = sigf(zi[n] + zh[n]);
  float z  = sigf(zi[H2+n] + zh[H2+n]);
  float nn = tanhf(zi[2*H2+n] + r*zh[2*H2+n]);
  float hold = cat_buf[b*3*H2 + n];
  float h = (1.0f - z)*nn + z*hold;
  cat_buf[b*3*H2 + n] = h;
  prebuf[((size_t)b*Tt + t)*H2 + n] = h;
}

// ================= attention queries (coalesced) =================
// grid 128 = ng(16 x 64n) x bg(8 x 4b)
__global__ __launch_bounds__(256) void qq_k(
    const float* __restrict__ cat_buf, const float* __restrict__ Wea,
    const float* __restrict__ Wda, float* __restrict__ q, float* __restrict__ qd)
{
  int bx = blockIdx.x;
  int ng = bx & 15, bg = bx >> 4;
  int nl = threadIdx.x & 63, bl = threadIdx.x >> 6;
  int n = ng*64 + nl, b = bg*4 + bl;
  const float* hr = cat_buf + b*3*H2;
  float s1 = 0.f, s2 = 0.f;
  #pragma unroll 4
  for (int k = 0; k < H2; ++k) {
    float hv = hr[k];
    s1 = fmaf(hv, Wea[(size_t)k*H2+n], s1);
    s2 = fmaf(hv, Wda[(size_t)k*H2+n], s2);
  }
  q[b*H2+n] = s1; qd[b*H2+n] = s2;
}

// ================= attention scores (float4) =================
__global__ __launch_bounds__(256) void att_sc_k(
    const float* __restrict__ q, const float* __restrict__ qd,
    const float* __restrict__ enc_out, const float* __restrict__ prebuf,
    float* __restrict__ esc, float* __restrict__ ed, int t)
{
  int w = blockIdx.x*4 + (threadIdx.x >> 6);
  int lane = threadIdx.x & 63;
  int b = w / 464;
  int row = w - b*464;
  if (b >= Bb) return;
  float s = 0.0f;
  if (row < Lmax) {
    const float4* qr = (const float4*)(q + b*H2);
    const float4* er = (const float4*)(enc_out + ((size_t)b*Lmax + row)*H2);
    #pragma unroll
    for (int j = 0; j < 4; ++j) {
      float4 a = qr[lane + 64*j], e = er[lane + 64*j];
      s += a.x*e.x + a.y*e.y + a.z*e.z + a.w*e.w;
    }
  } else {
    int tp = row - Lmax;
    if (tp >= t) { if (lane==0) ed[b*Tt+tp] = 0.0f; return; }
    const float4* qr = (const float4*)(qd + b*H2);
    const float4* pr = (const float4*)(prebuf + ((size_t)b*Tt + tp)*H2);
    #pragma unroll
    for (int j = 0; j < 4; ++j) {
      float4 a = qr[lane + 64*j], e = pr[lane + 64*j];
      s += a.x*e.x + a.y*e.y + a.z*e.z + a.w*e.w;
    }
  }
  for (int o = 32; o > 0; o >>= 1) s += __shfl_xor(s, o);
  if (lane == 0) { if (row < Lmax) esc[b*Lmax+row] = s; else ed[b*Tt + (row-Lmax)] = s; }
}

// ================= temporal normalize + intra-dec softmax =================
__global__ __launch_bounds__(256) void att_norm_k(
    const float* __restrict__ esc, float* __restrict__ accum,
    float* __restrict__ enc_att, const float* __restrict__ ed,
    float* __restrict__ dec_att, int t)
{
  __shared__ float red[256];
  int b = blockIdx.x, tid = threadIdx.x;
  float loc = 0.0f;
  for (int l = tid; l < Lmax; l += 256) {
    float ee = expf(esc[b*Lmax + l]);
    float a  = accum[b*Lmax + l];
    float un = (t == 0) ? ee : ee / (a + 1e-10f);
    accum[b*Lmax + l] = a + ee;
    enc_att[b*Lmax + l] = un;
    loc += un;
  }
  red[tid] = loc; __syncthreads();
  for (int s = 128; s > 0; s >>= 1) { if (tid < s) red[tid] += red[tid+s]; __syncthreads(); }
  float inv = 1.0f / red[0];
  for (int l = tid; l < Lmax; l += 256) enc_att[b*Lmax+l] *= inv;
  if (tid < 64) {
    int lane = tid;
    if (t == 0) { dec_att[b*Tt+lane] = 0.0f; }
    else {
      float v = (lane < t) ? ed[b*Tt+lane] : -INFINITY;
      float m = v;
      for (int o = 32; o > 0; o >>= 1) m = fmaxf(m, __shfl_xor(m, o));
      float p = (lane < t) ? expf(v - m) : 0.0f;
      float ssum = p;
      for (int o = 32; o > 0; o >>= 1) ssum += __shfl_xor(ssum, o);
      dec_att[b*Tt+lane] = p / ssum;
    }
  }
}

// ================= contexts + fused p_gen partial =================
__global__ __launch_bounds__(256) void ctx_k(
    const float* __restrict__ enc_att, const float* __restrict__ enc_out,
    const float* __restrict__ dec_att, const float* __restrict__ prebuf,
    float* __restrict__ cat_buf, const float* __restrict__ Wp,
    float* __restrict__ pg_raw, int t)
{
  __shared__ float red[256];
  int idx = blockIdx.x*256 + threadIdx.x;  // 32768; each block: one b, 256 consecutive k
  int b = idx >> 10, k = idx & 1023;
  float ec = 0.0f;
  const float* ar = enc_att + b*Lmax;
  const float* er = enc_out + (size_t)b*Lmax*H2 + k;
  for (int l = 0; l < Lmax; ++l) ec = fmaf(ar[l], er[(size_t)l*H2], ec);
  float dc = 0.0f;
  const float* dr = dec_att + b*Tt;
  const float* pr = prebuf + (size_t)b*Tt*H2 + k;
  for (int tp = 0; tp < t; ++tp) dc = fmaf(dr[tp], pr[(size_t)tp*H2], dc);
  cat_buf[b*3*H2 + H2   + k] = ec;
  cat_buf[b*3*H2 + 2*H2 + k] = dc;
  float hv = cat_buf[b*3*H2 + k];
  float part = hv*Wp[k] + ec*Wp[H2+k] + dc*Wp[2*H2+k];
  red[threadIdx.x] = part; __syncthreads();
  for (int s = 128; s > 0; s >>= 1) { if (threadIdx.x < s) red[threadIdx.x] += red[threadIdx.x+s]; __syncthreads(); }
  if (threadIdx.x == 0) atomicAdd(&pg_raw[b], red[0]);
}

// ================= Wv bf16 pack =================
__global__ __launch_bounds__(256) void pack_wv_k(const float* __restrict__ Wv, unsigned short* __restrict__ Wbf)
{
  size_t i = ((size_t)blockIdx.x*256 + threadIdx.x)*4;
  #pragma unroll
  for (int j = 0; j < 4; ++j) {
    unsigned int u = __float_as_uint(Wv[i+j]);
    u = (u + 0x7fffu + ((u >> 16) & 1u)) >> 16;   // RNE
    Wbf[i+j] = (unsigned short)u;
  }
}

// ================= logits GEMM, bf16 weights =================
__global__ __launch_bounds__(256) void wv_mm_bf_k(
    const float* __restrict__ cat_buf, const unsigned short* __restrict__ Wbf,
    const float* __restrict__ bv, float* __restrict__ logits)
{
  __shared__ float As[32][33];
  __shared__ float Wsh[32][128];
  int tid = threadIdx.x;
  int n0 = blockIdx.x*128;
  int tx = tid & 31, ty = tid >> 5;
  float acc[4][4] = {};
  for (int k0 = 0; k0 < 3*H2; k0 += 32) {
    #pragma unroll
    for (int i = 0; i < 4; ++i) {
      int a = tid*4+i;
      As[a>>5][a&31] = cat_buf[(size_t)(a>>5)*3*H2 + k0 + (a&31)];
    }
    #pragma unroll
    for (int j = 0; j < 8; ++j) {
      int a = j*256 + tid;              // 2048 uint2-pairs: 32 rows x 64
      int row = a >> 6, c2 = (a & 63)*2;
      const unsigned int* wr = (const unsigned int*)(Wbf + (size_t)(k0+row)*Vv + n0);
      unsigned int u = wr[a & 63];
      Wsh[row][c2]   = bf2f(u & 0xffffu);
      Wsh[row][c2+1] = bf2f(u >> 16);
    }
    __syncthreads();
    #pragma unroll
    for (int kk = 0; kk < 32; ++kk) {
      float a0 = As[ty*4+0][kk], a1 = As[ty*4+1][kk], a2 = As[ty*4+2][kk], a3 = As[ty*4+3][kk];
      float w0 = Wsh[kk][tx*4+0], w1 = Wsh[kk][tx*4+1], w2 = Wsh[kk][tx*4+2], w3 = Wsh[kk][tx*4+3];
      acc[0][0]=fmaf(a0,w0,acc[0][0]); acc[0][1]=fmaf(a0,w1,acc[0][1]); acc[0][2]=fmaf(a0,w2,acc[0][2]); acc[0][3]=fmaf(a0,w3,acc[0][3]);
      acc[1][0]=fmaf(a1,w0,acc[1][0]); acc[1][1]=fmaf(a1,w1,acc[1][1]); acc[1][2]=fmaf(a1,w2,acc[1][2]); acc[1][3]=fmaf(a1,w3,acc[1][3]);
      acc[2][0]=fmaf(a2,w0,acc[2][0]); acc[2][1]=fmaf(a2,w1,acc[2][1]); acc[2][2]=fmaf(a2,w2,acc[2][2]); acc[2][3]=fmaf(a2,w3,acc[2][3]);
      acc[3][0]=fmaf(a3,w0,acc[3][0]); acc[3][1]=fmaf(a3,w1,acc[3][1]); acc[3][2]=fmaf(a3,w2,acc[3][2]); acc[3][3]=fmaf(a3,w3,acc[3][3]);
    }
    __syncthreads();
  }
  #pragma unroll
  for (int i = 0; i < 4; ++i)
    #pragma unroll
    for (int j = 0; j < 4; ++j) {
      int n = n0 + tx*4 + j;
      logits[(size_t)(ty*4+i)*Vv + n] = acc[i][j] + bv[n];
    }
}

// ================= logits GEMM, fp32 fallback =================
__global__ __launch_bounds__(256) void wv_mm_k(
    const float* __restrict__ cat_buf, const float* __restrict__ Wv,
    const float* __restrict__ bv, float* __restrict__ logits)
{
  __shared__ float As[32][33];
  __shared__ float Wsh[32][128];
  int tid = threadIdx.x;
  int n0 = blockIdx.x*128;
  int tx = tid & 31, ty = tid >> 5;
  float acc[4][4] = {};
  for (int k0 = 0; k0 < 3*H2; k0 += 32) {
    #pragma unroll
    for (int i = 0; i < 4; ++i) {
      int a = tid*4+i;
      As[a>>5][a&31] = cat_buf[(size_t)(a>>5)*3*H2 + k0 + (a&31)];
    }
    #pragma unroll
    for (int j = 0; j < 16; ++j) {
      int a = j*256+tid;
      Wsh[a>>7][a&127] = Wv[(size_t)(k0+(a>>7))*Vv + n0 + (a&127)];
    }
    __syncthreads();
    #pragma unroll
    for (int kk = 0; kk < 32; ++kk) {
      float a0 = As[ty*4+0][kk], a1 = As[ty*4+1][kk], a2 = As[ty*4+2][kk], a3 = As[ty*4+3][kk];
      float w0 = Wsh[kk][tx*4+0], w1 = Wsh[kk][tx*4+1], w2 = Wsh[kk][tx*4+2], w3 = Wsh[kk][tx*4+3];
      acc[0][0]=fmaf(a0,w0,acc[0][0]); acc[0][1]=fmaf(a0,w1,acc[0][1]); acc[0][2]=fmaf(a0,w2,acc[0][2]); acc[0][3]=fmaf(a0,w3,acc[0][3]);
      acc[1][0]=fmaf(a1,w0,acc[1][0]); acc[1][1]=fmaf(a1,w1,acc[1][1]); acc[1][2]=fmaf(a1,w2,acc[1][2]); acc[1][3]=fmaf(a1,w3,acc[1][3]);
      acc[2][0]=fmaf(a2,w0,acc[2][0]); acc[2][1]=fmaf(a2,w1,acc[2][1]); acc[2][2]=fmaf(a2,w2,acc[2][2]); acc[2][3]=fmaf(a2,w3,acc[2][3]);
      acc[3][0]=fmaf(a3,w0,acc[3][0]); acc[3][1]=fmaf(a3,w1,acc[3][1]); acc[3][2]=fmaf(a3,w2,acc[3][2]); acc[3][3]=fmaf(a3,w3,acc[3][3]);
    }
    __syncthreads();
  }
  #pragma unroll
  for (int i = 0; i < 4; ++i)
    #pragma unroll
    for (int j = 0; j < 4; ++j) {
      int n = n0 + tx*4 + j;
      logits[(size_t)(ty*4+i)*Vv + n] = acc[i][j] + bv[n];
    }
}

// ================= fused softmax + pointer-scatter + argmax + loss =================
// block per b. Never materializes final distribution: vocab candidates from logits,
// pointer candidates from <=400 touched bins (deduped in LDS, deterministic order).
__global__ __launch_bounds__(256) void final_k(
    const float* __restrict__ logits, const float* __restrict__ pg_raw,
    const float* __restrict__ bps, const int* __restrict__ ev,
    const float* __restrict__ enc_att, const int* __restrict__ tgt_y,
    float* __restrict__ out, int* __restrict__ dec_in, int t)
{
  __shared__ float rf[256];
  __shared__ int   ri[256];
  __shared__ float tm[256];
  __shared__ int   ev_s[Lmax];
  __shared__ float pv_s[Lmax];
  __shared__ float m_sh, sc_sh, pg_sh;
  int b = blockIdx.x, tid = threadIdx.x;
  const float*  lr  = logits + (size_t)b*Vv;
  const float4* lr4 = (const float4*)lr;
  // pass A: max
  float m = -1e30f;
  for (int i = tid; i < Vv/4; i += 256) {
    float4 v = lr4[i];
    m = fmaxf(m, fmaxf(fmaxf(v.x,v.y), fmaxf(v.z,v.w)));
  }
  rf[tid] = m; __syncthreads();
  for (int s = 128; s > 0; s >>= 1) { if (tid < s) rf[tid] = fmaxf(rf[tid], rf[tid+s]); __syncthreads(); }
  m = rf[0]; __syncthreads();
  // pass B: sum exp
  float ssum = 0.f;
  for (int i = tid; i < Vv/4; i += 256) {
    float4 v = lr4[i];
    ssum += expf(v.x-m) + expf(v.y-m) + expf(v.z-m) + expf(v.w-m);
  }
  rf[tid] = ssum; __syncthreads();
  for (int s = 128; s > 0; s >>= 1) { if (tid < s) rf[tid] += rf[tid+s]; __syncthreads(); }
  if (tid == 0) {
    float pg = sigf(pg_raw[b] + bps[0]);
    pg_sh = pg; sc_sh = (1.0f - pg) / rf[0]; m_sh = m;
  }
  for (int l = tid; l < Lmax; l += 256) ev_s[l] = ev[b*Lmax + l];
  __syncthreads();
  float scale = sc_sh, pg = pg_sh; m = m_sh;
  for (int l = tid; l < Lmax; l += 256) pv_s[l] = pg * enc_att[b*Lmax + l];
  __syncthreads();
  // pass C: vocab argmax (first-index tiebreak; indices ascend per thread)
  float best = -1e30f; int bi = 0x7fffffff;
  for (int i = tid; i < Vv/4; i += 256) {
    float4 v = lr4[i];
    float p0 = expf(v.x-m)*scale, p1 = expf(v.y-m)*scale, p2 = expf(v.z-m)*scale, p3 = expf(v.w-m)*scale;
    int n = 4*i;
    if (p0 > best) { best = p0; bi = n; }
    if (p1 > best || (p1 == best && n+1 < bi)) { best = p1; bi = n+1; }
    if (p2 > best || (p2 == best && n+2 < bi)) { best = p2; bi = n+2; }
    if (p3 > best || (p3 == best && n+3 < bi)) { best = p3; bi = n+3; }
  }
  // touched pointer bins + target pointer mass
  int tgt = tgt_y[b*Tt + t];
  float ptm = 0.f;
  for (int l = tid; l < Lmax; l += 256) {
    int e = ev_s[l];
    float tot = 0.f;
    for (int l2 = 0; l2 < Lmax; ++l2) if (ev_s[l2] == e) tot += pv_s[l2];
    float vvv = tot + ((e < Vv) ? expf(lr[e]-m)*scale : 0.f);
    if (vvv > best || (vvv == best && e < bi)) { best = vvv; bi = e; }
    ptm += (e == tgt) ? pv_s[l] : 0.f;
  }
  rf[tid] = best; ri[tid] = bi; tm[tid] = ptm; __syncthreads();
  for (int s = 128; s > 0; s >>= 1) {
    if (tid < s) {
      float v2 = rf[tid+s]; int i2 = ri[tid+s];
      if (v2 > rf[tid] || (v2 == rf[tid] && i2 < ri[tid])) { rf[tid] = v2; ri[tid] = i2; }
      tm[tid] += tm[tid+s];
    }
    __syncthreads();
  }
  if (tid == 0) {
    int am = ri[0];
    float fr_tgt = expf(lr[tgt]-m)*scale + tm[0];
    float loss = (tgt != PAD_ID) ? -logf(fr_tgt + 1e-12f) : 0.0f;
    out[b*Tt + t] = (float)am;
    out[Bb*Tt + b*Tt + t] = loss;
    dec_in[b] = (am >= Vv) ? UNK_ID : am;
  }
}

extern "C" void kernel_launch(void* const* d_in, const int* in_sizes, int n_in,
                              void* d_out, int out_size, void* d_ws, size_t ws_size,
                              hipStream_t stream)
{
  const int*   x    = (const int*)  d_in[0];
  const int*   tgt  = (const int*)  d_in[2];
  const int*   ev   = (const int*)  d_in[3];
  const float* emb  = (const float*)d_in[5];
  const float* Wi_f = (const float*)d_in[6];
  const float* Wh_f = (const float*)d_in[7];
  const float* b_f  = (const float*)d_in[8];
  const float* Wi_b = (const float*)d_in[9];
  const float* Wh_b = (const float*)d_in[10];
  const float* b_b  = (const float*)d_in[11];
  const float* dWi  = (const float*)d_in[12];
  const float* dWh  = (const float*)d_in[13];
  const float* db   = (const float*)d_in[14];
  const float* Wea  = (const float*)d_in[15];
  const float* Wda  = (const float*)d_in[16];
  const float* Wv   = (const float*)d_in[17];
  const float* bv   = (const float*)d_in[18];
  const float* Wp   = (const float*)d_in[19];
  const float* bp   = (const float*)d_in[20];
  float* out = (float*)d_out;

  float* ws = (float*)d_ws;
  size_t off = 0;
  float* enc_out = ws + off; off += (size_t)Bb*Lmax*H2;     // 13,107,200
  float* c_buf   = ws + off; off += 2*Bb*Hh;                // 32,768
  float4* wip    = (float4*)(ws + off); off += 2*256*512*4; // 1,048,576
  float4* whp    = (float4*)(ws + off); off += 2*512*512*4; // 2,097,152
  float4* biasp  = (float4*)(ws + off); off += 2*512*4;     // 4,096
  float* cat_buf = ws + off; off += Bb*3*H2;
  float* prebuf  = ws + off; off += (size_t)Bb*Tt*H2;
  float* accum   = ws + off; off += Bb*Lmax;
  float* zi_buf  = ws + off; off += Bb*3*H2;
  float* zh_buf  = ws + off; off += Bb*3*H2;
  float* q       = ws + off; off += Bb*H2;
  float* qd      = ws + off; off += Bb*H2;
  float* esc     = ws + off; off += Bb*Lmax;
  float* enc_att = ws + off; off += Bb*Lmax;
  float* ed      = ws + off; off += Bb*Tt;
  float* dec_att = ws + off; off += Bb*Tt;
  float* pg_raw  = ws + off; off += 32;
  float* logits  = ws + off; off += (size_t)Bb*Vv;
  int*   dec_in  = (int*)(ws + off); off += 32;
  unsigned short* Wbf = (unsigned short*)(ws + off);
  size_t need_bf16 = off*4 + (size_t)3*H2*Vv*2;             // bytes
  int use_bf16 = (ws_size >= need_bf16 + (64u<<10)) ? 1 : 0;

  // one-time packs (re-done every call: ws is re-poisoned)
  pack_enc_k<<<2048,256,0,stream>>>(Wi_f,Wh_f,b_f,Wi_b,Wh_b,b_b,wip,whp,biasp);
  if (use_bf16) pack_wv_k<<<96000,256,0,stream>>>(Wv, Wbf);

  for (int t = 0; t < Lmax; ++t)
    enc_step2_k<<<256,512,0,stream>>>(wip,whp,biasp,emb,x,c_buf,enc_out,t);

  init_dec_k<<<128,256,0,stream>>>(enc_out,cat_buf,accum,dec_in);

  for (int t = 0; t < Tt; ++t) {
    gru_mm_k  <<<384,256,0,stream>>>(emb,dec_in,cat_buf,dWi,dWh,db,zi_buf,zh_buf,pg_raw);
    gru_comb_k<<<128,256,0,stream>>>(zi_buf,zh_buf,cat_buf,prebuf,t);
    qq_k      <<<128,256,0,stream>>>(cat_buf,Wea,Wda,q,qd);
    att_sc_k  <<<3712,256,0,stream>>>(q,qd,enc_out,prebuf,esc,ed,t);
    att_norm_k<<<32,256,0,stream>>>(esc,accum,enc_att,ed,dec_att,t);
    ctx_k     <<<128,256,0,stream>>>(enc_att,enc_out,dec_att,prebuf,cat_buf,Wp,pg_raw,t);
    if (use_bf16) wv_mm_bf_k<<<250,256,0,stream>>>(cat_buf,Wbf,bv,logits);
    else          wv_mm_k   <<<250,256,0,stream>>>(cat_buf,Wv,bv,logits);
    final_k   <<<32,256,0,stream>>>(logits,pg_raw,bp,ev,enc_att,tgt,out,dec_in,t);
  }
}